// Round 3
// baseline (16426.044 us; speedup 1.0000x reference)
//
#include <hip/hip_runtime.h>
#include <hip/hip_bf16.h>

#define VSZ 128
#define EMBD 64
#define HSZ 512
#define BSZ 256
#define TLEN 512
#define NBLK 72              // 16 P + 16 L0 + 16 L1a + 16 L1b + 8 FC

typedef __attribute__((ext_vector_type(8))) short short8;
typedef __attribute__((ext_vector_type(4))) float f32x4;
typedef __attribute__((ext_vector_type(4))) unsigned int u32x4;
typedef __hip_bfloat16 bf16;

#define SQ   ((size_t)HSZ*HSZ)

// ---- weight region (bf16 element offsets; identical to known-good layout) ----
#define O_WHH0HI ((size_t)0)
#define O_WHH0LO (O_WHH0HI + SQ)
#define O_WIH1HI (O_WHH0LO + SQ)
#define O_WIH1LO (O_WIH1HI + SQ)
#define O_WHH1HI (O_WIH1LO + SQ)
#define O_WHH1LO (O_WHH1HI + SQ)
#define O_WIH0HI (O_WHH1LO + SQ)                 // [N=512][K=64]
#define O_WIH0LO (O_WIH0HI + (size_t)HSZ*EMBD)
#define O_WFCHI  (O_WIH0LO + (size_t)HSZ*EMBD)   // [N=128][K=512]
#define O_WFCLO  (O_WFCHI + (size_t)VSZ*HSZ)
#define O_EMBHI  (O_WFCLO + (size_t)VSZ*HSZ)     // [128][64]
#define O_EMBLO  (O_EMBHI + (size_t)VSZ*EMBD)
// weights end at elem 1,785,856 -> byte 3,571,712

// ---- ring / counter region (byte offsets). total ws = 7,775,232 B
#define O_RINGB  ((size_t)3571712)
#define O_ERING  (O_RINGB)                        // fp32 [16 grp][2 slot][8192] lane-major
#define O_H0RING (O_RINGB + ((size_t)1<<20))      // u32  [16][2][8192] row-major packed hi|lo
#define O_ZRING  (O_RINGB + ((size_t)2<<20))      // fp32 lane-major
#define O_H1RING (O_RINGB + ((size_t)3<<20))      // u32 row-major packed
#define O_CTRB   (O_RINGB + ((size_t)4<<20))      // PROD[72][16] int, CONS[72][16] int

#define SLOTW 8192            // 4B elems per slot
#define GRPW  16384           // 2 slots
#define ASTR  1024            // A-plane row stride bytes (swizzled, no pad)
#define APLANE 16384          // 16 rows
#define SMEMSZ 65536

static __device__ __forceinline__ short8 ld8(const bf16* p) { return *(const short8*)p; }
static __device__ __forceinline__ float b2f(bf16 v) { return __bfloat162float(v); }
#define MFMA(a,b,c) __builtin_amdgcn_mfma_f32_16x16x32_bf16((a),(b),(c),0,0,0)

// ---- device-scope primitives: ALL loads wait inside the asm block ----
static __device__ __forceinline__ void st4_sc(void* p, unsigned v) {
    asm volatile("global_store_dword %0, %1, off sc0 sc1" :: "v"(p), "v"(v) : "memory");
}
static __device__ __forceinline__ void st4i(int* p, int v) { st4_sc(p, (unsigned)v); }
// 64B contiguous sc store (lane-major E/z slots). NOTE: offset: must precede sc flags.
static __device__ __forceinline__ void st16sc(float* p, const f32x4* v) {
    asm volatile(
        "global_store_dwordx4 %0, %1, off sc0 sc1\n\t"
        "global_store_dwordx4 %0, %2, off offset:16 sc0 sc1\n\t"
        "global_store_dwordx4 %0, %3, off offset:32 sc0 sc1\n\t"
        "global_store_dwordx4 %0, %4, off offset:48 sc0 sc1"
        :: "v"(p), "v"(v[0]), "v"(v[1]), "v"(v[2]), "v"(v[3]) : "memory");
}
// 64B contiguous sc load + wait
static __device__ __forceinline__ void ld64sc(const float* p, f32x4* v) {
    asm volatile(
        "global_load_dwordx4 %0, %4, off sc0 sc1\n\t"
        "global_load_dwordx4 %1, %4, off offset:16 sc0 sc1\n\t"
        "global_load_dwordx4 %2, %4, off offset:32 sc0 sc1\n\t"
        "global_load_dwordx4 %3, %4, off offset:48 sc0 sc1\n\t"
        "s_waitcnt vmcnt(0)"
        : "=&v"(v[0]), "=&v"(v[1]), "=&v"(v[2]), "=&v"(v[3])
        : "v"(p) : "memory");
}
// one 32KB slot coalesced across 512 threads (4 x dwordx4 each) + wait
static __device__ __forceinline__ void pref4sc(const unsigned* base, int tid, u32x4* v) {
    const unsigned* p0 = base + 0*2048 + tid*4;
    const unsigned* p1 = base + 1*2048 + tid*4;
    const unsigned* p2 = base + 2*2048 + tid*4;
    const unsigned* p3 = base + 3*2048 + tid*4;
    asm volatile(
        "global_load_dwordx4 %0, %4, off sc0 sc1\n\t"
        "global_load_dwordx4 %1, %5, off sc0 sc1\n\t"
        "global_load_dwordx4 %2, %6, off sc0 sc1\n\t"
        "global_load_dwordx4 %3, %7, off sc0 sc1\n\t"
        "s_waitcnt vmcnt(0)"
        : "=&v"(v[0]), "=&v"(v[1]), "=&v"(v[2]), "=&v"(v[3])
        : "v"(p0), "v"(p1), "v"(p2), "v"(p3) : "memory");
}
// two slots (FC) in one round trip
static __device__ __forceinline__ void pref8sc(const unsigned* b1, const unsigned* b2,
                                               int tid, u32x4* v) {
    const unsigned* q0 = b1 + 0*2048 + tid*4; const unsigned* q1 = b1 + 1*2048 + tid*4;
    const unsigned* q2 = b1 + 2*2048 + tid*4; const unsigned* q3 = b1 + 3*2048 + tid*4;
    const unsigned* q4 = b2 + 0*2048 + tid*4; const unsigned* q5 = b2 + 1*2048 + tid*4;
    const unsigned* q6 = b2 + 2*2048 + tid*4; const unsigned* q7 = b2 + 3*2048 + tid*4;
    asm volatile(
        "global_load_dwordx4 %0, %8, off sc0 sc1\n\t"
        "global_load_dwordx4 %1, %9, off sc0 sc1\n\t"
        "global_load_dwordx4 %2, %10, off sc0 sc1\n\t"
        "global_load_dwordx4 %3, %11, off sc0 sc1\n\t"
        "global_load_dwordx4 %4, %12, off sc0 sc1\n\t"
        "global_load_dwordx4 %5, %13, off sc0 sc1\n\t"
        "global_load_dwordx4 %6, %14, off sc0 sc1\n\t"
        "global_load_dwordx4 %7, %15, off sc0 sc1\n\t"
        "s_waitcnt vmcnt(0)"
        : "=&v"(v[0]), "=&v"(v[1]), "=&v"(v[2]), "=&v"(v[3]),
          "=&v"(v[4]), "=&v"(v[5]), "=&v"(v[6]), "=&v"(v[7])
        : "v"(q0), "v"(q1), "v"(q2), "v"(q3), "v"(q4), "v"(q5), "v"(q6), "v"(q7)
        : "memory");
}
// wave-0 polls one counter, then block-wide sync
static __device__ __forceinline__ void pollw(const int* p, int need, int wv) {
    if (wv == 0) {
        for (int it = 0; it < (1 << 17); ++it) {
            int v;
            asm volatile("global_load_dword %0, %1, off sc0 sc1\n\t"
                         "s_waitcnt vmcnt(0)" : "=v"(v) : "v"(p) : "memory");
            if (v >= need) break;
            __builtin_amdgcn_s_sleep(1);
        }
    }
    __syncthreads();
}
// unpack u32(hi | lo<<16) row-major slot data into swizzled hi/lo A-planes
static __device__ __forceinline__ void awrite4(char* Ahi, char* Alo, int tid,
                                               const u32x4* v, int rowoff) {
    const int colb8 = (tid & 127) * 8;            // byte offset of this thread's 4-col group
#pragma unroll
    for (int j = 0; j < 4; j++) {
        int row = rowoff + j*4 + (tid >> 7);
        int off = row * ASTR + (colb8 ^ ((row & 7) << 4));
        unsigned a = v[j][0], b = v[j][1], c = v[j][2], d = v[j][3];
        uint2 hi, lo;
        hi.x = (a & 0xffffu) | (b << 16);  hi.y = (c & 0xffffu) | (d << 16);
        lo.x = (a >> 16) | (b & 0xffff0000u); lo.y = (c >> 16) | (d & 0xffff0000u);
        *(uint2*)(Ahi + off) = hi;
        *(uint2*)(Alo + off) = lo;
    }
}
// K=512 hi/lo-split MFMA loop: A from swizzled LDS planes, B streamed from L2
static __device__ __forceinline__ void kloop512(const char* Ahi, const char* Alo,
                                                const bf16* Whi, const bf16* Wlo,
                                                int l15, int quad, int colbase,
                                                f32x4 accA[4], f32x4 accB[4]) {
    const int swz = (l15 & 7) << 4;
    const int arow = l15 * ASTR;
    const bf16* wh[4]; const bf16* wl[4];
#pragma unroll
    for (int ni = 0; ni < 4; ni++) {
        int c = colbase + ni*16 + l15;
        wh[ni] = Whi + (size_t)c * HSZ;
        wl[ni] = Wlo + (size_t)c * HSZ;
    }
#pragma unroll 4
    for (int kc = 0; kc < 16; kc++) {
        const int aoff = arow + ((kc*64 + quad*16) ^ swz);
        short8 ah = *(const short8*)(Ahi + aoff);
        short8 al = *(const short8*)(Alo + aoff);
#pragma unroll
        for (int ni = 0; ni < 4; ni++) {
            short8 bh = ld8(wh[ni] + kc*32 + quad*8);
            short8 bl = ld8(wl[ni] + kc*32 + quad*8);
            accA[ni] = MFMA(ah, bh, accA[ni]);
            accB[ni] = MFMA(al, bh, accB[ni]);
            accB[ni] = MFMA(ah, bl, accB[ni]);
        }
    }
}

// ---- prep: split/transpose weights + zero counters ----
__global__ void k_prep(const float* __restrict__ emb, const float* __restrict__ Wih0,
                       const float* __restrict__ Whh0, const float* __restrict__ Wih1,
                       const float* __restrict__ Whh1, const float* __restrict__ Wfc,
                       bf16* __restrict__ ws) {
    int j = blockIdx.x * blockDim.x + threadIdx.x;
    const int SQi = HSZ * HSZ;
    if (j < SQi) {
        int n = j / HSZ, k = j - n * HSZ;
        float w = Whh0[k * HSZ + n];
        bf16 hi = __float2bfloat16(w);
        ws[O_WHH0HI + j] = hi; ws[O_WHH0LO + j] = __float2bfloat16(w - b2f(hi));
        return;
    }
    j -= SQi;
    if (j < SQi) {
        int n = j / HSZ, k = j - n * HSZ;
        float w = Wih1[k * HSZ + n];
        bf16 hi = __float2bfloat16(w);
        ws[O_WIH1HI + j] = hi; ws[O_WIH1LO + j] = __float2bfloat16(w - b2f(hi));
        return;
    }
    j -= SQi;
    if (j < SQi) {
        int n = j / HSZ, k = j - n * HSZ;
        float w = Whh1[k * HSZ + n];
        bf16 hi = __float2bfloat16(w);
        ws[O_WHH1HI + j] = hi; ws[O_WHH1LO + j] = __float2bfloat16(w - b2f(hi));
        return;
    }
    j -= SQi;
    if (j < HSZ * EMBD) {
        int n = j / EMBD, k = j - n * EMBD;
        float w = Wih0[k * HSZ + n];
        bf16 hi = __float2bfloat16(w);
        ws[O_WIH0HI + j] = hi; ws[O_WIH0LO + j] = __float2bfloat16(w - b2f(hi));
        return;
    }
    j -= HSZ * EMBD;
    if (j < VSZ * HSZ) {
        int n = j / HSZ, k = j - n * HSZ;
        float w = Wfc[k * VSZ + n];
        bf16 hi = __float2bfloat16(w);
        ws[O_WFCHI + j] = hi; ws[O_WFCLO + j] = __float2bfloat16(w - b2f(hi));
        return;
    }
    j -= VSZ * HSZ;
    if (j < VSZ * EMBD) {
        float w = emb[j];
        bf16 hi = __float2bfloat16(w);
        ws[O_EMBHI + j] = hi; ws[O_EMBLO + j] = __float2bfloat16(w - b2f(hi));
        return;
    }
    j -= VSZ * EMBD;
    if (j < NBLK * 16 * 2) ((int*)((char*)ws + O_CTRB))[j] = 0;   // prod + cons
}

// ---- persistent 5-stage pipeline, depth-2 rings, blocking sc-loads ----
__global__ __launch_bounds__(512) void k_persist(
    const int* __restrict__ x,
    const float* __restrict__ bih0, const float* __restrict__ bhh0,
    const float* __restrict__ bih1, const float* __restrict__ bhh1,
    const float* __restrict__ bfc,
    bf16* __restrict__ ws, float* __restrict__ out)
{
    extern __shared__ char smem[];
    const int tid = (int)threadIdx.x;
    const int lane = tid & 63;
    const int wv   = tid >> 6;
    const int l15  = lane & 15;
    const int quad = lane >> 4;
    const int bid  = (int)blockIdx.x;

    int* PROD = (int*)((char*)ws + O_CTRB);
    int* CONS = PROD + NBLK * 16;

    if (bid < 16) {
        // ============ stage P: E[t] = emb[x[:,t]] @ Wih0 + bih0 + bhh0 ============
        const int r = bid, mb = r * 16;
        const bf16* WThi = ws + O_WIH0HI; const bf16* WTlo = ws + O_WIH0LO;
        const bf16* embhi = ws + O_EMBHI; const bf16* emblo = ws + O_EMBLO;
        char* Ahi = smem; char* Alo = smem + APLANE;
        int*  xbuf = (int*)(smem + 2 * APLANE);
        int* myprod = PROD + r * 16;
        const int* ccons = CONS + (16 + r) * 16;          // L0's consumed count
        const int colbase = wv * 64;
        float bias[4];
#pragma unroll
        for (int ni = 0; ni < 4; ni++) { int c = colbase + ni*16 + l15; bias[ni] = bih0[c] + bhh0[c]; }
        float* ering = (float*)((char*)ws + O_ERING) + (size_t)r * GRPW;

        for (int t = 0; t < TLEN; ++t) {
            if (t >= 2) pollw(ccons, t - 1, wv);          // depth-2 backpressure
            if (tid < 16) xbuf[tid] = x[(size_t)(mb + tid) * TLEN + t];
            __syncthreads();
            if (tid < 128) {                               // build swizzled A-planes
                int row = tid >> 3, oct = tid & 7;
                int xr = xbuf[row];
                int off = row * ASTR + ((oct * 16) ^ ((row & 7) << 4));
                *(short8*)(Ahi + off) = ld8(embhi + (size_t)xr * EMBD + oct * 8);
                *(short8*)(Alo + off) = ld8(emblo + (size_t)xr * EMBD + oct * 8);
            }
            __syncthreads();
            const int swz = (l15 & 7) << 4;
            f32x4 accA[4] = {}, accB[4] = {};
#pragma unroll
            for (int kc = 0; kc < 2; kc++) {
                int aoff = l15 * ASTR + ((kc*64 + quad*16) ^ swz);
                short8 ah = *(const short8*)(Ahi + aoff);
                short8 al = *(const short8*)(Alo + aoff);
#pragma unroll
                for (int ni = 0; ni < 4; ni++) {
                    int c = colbase + ni*16 + l15;
                    short8 bh = ld8(WThi + (size_t)c * EMBD + kc*32 + quad*8);
                    short8 bl = ld8(WTlo + (size_t)c * EMBD + kc*32 + quad*8);
                    accA[ni] = MFMA(ah, bh, accA[ni]);
                    accB[ni] = MFMA(al, bh, accB[ni]);
                    accB[ni] = MFMA(ah, bl, accB[ni]);
                }
            }
            f32x4 ev[4];
#pragma unroll
            for (int ni = 0; ni < 4; ni++)
#pragma unroll
                for (int rr = 0; rr < 4; rr++) ev[ni][rr] = accA[ni][rr] + accB[ni][rr] + bias[ni];
            st16sc(ering + (size_t)(t & 1) * SLOTW + tid * 16, ev);   // lane-major
            asm volatile("s_waitcnt vmcnt(0)" ::: "memory");
            __syncthreads();
            if (tid == 0) st4i(myprod, t + 1);
        }

    } else if (bid < 32) {
        // ===== stage L0: h0[t] = tanh(E[t] + h0[t-1]@Whh0); state in LDS dbuf =====
        const int r = bid - 16;
        const bf16* Whi = ws + O_WHH0HI; const bf16* Wlo = ws + O_WHH0LO;
        char* A0 = smem;                                  // [buf0hi,buf0lo,buf1hi,buf1lo]
        int* myprod = PROD + (16 + r) * 16;
        int* mycons = CONS + (16 + r) * 16;
        const int* pprod = PROD + r * 16;                 // P
        const int* ccons = CONS + (32 + r) * 16;          // L1a consumed
        const float* ering = (const float*)((char*)ws + O_ERING) + (size_t)r * GRPW;
        unsigned* h0ring = (unsigned*)((char*)ws + O_H0RING) + (size_t)r * GRPW;
        const int colbase = wv * 64;

        for (int i = tid * 4; i < 2 * APLANE; i += 512 * 4) *(unsigned*)(A0 + i) = 0u;  // h0[-1]=0
        __syncthreads();

        for (int t = 0; t < TLEN; ++t) {
            const int cur = t & 1;
            const char* Ahi = A0 + (cur*2 + 0) * APLANE;
            const char* Alo = A0 + (cur*2 + 1) * APLANE;
            char* AhiN = A0 + ((cur^1)*2 + 0) * APLANE;
            char* AloN = A0 + ((cur^1)*2 + 1) * APLANE;
            if (t >= 2) pollw(ccons, t - 1, wv);          // L1a done with slot t-2
            f32x4 accA[4] = {}, accB[4] = {};
            kloop512(Ahi, Alo, Whi, Wlo, l15, quad, colbase, accA, accB);
            pollw(pprod, t + 1, wv);                      // E[t] ready (steady state: instant)
            f32x4 ec[4];
            ld64sc(ering + (size_t)(t & 1) * SLOTW + tid * 16, ec);
            unsigned* slot = h0ring + (size_t)(t & 1) * SLOTW;
#pragma unroll
            for (int ni = 0; ni < 4; ni++) {
                int c = colbase + ni*16 + l15;
#pragma unroll
                for (int rr = 0; rr < 4; rr++) {
                    int row = quad*4 + rr;
                    float v = tanhf(accA[ni][rr] + accB[ni][rr] + ec[ni][rr]);
                    bf16 hb = __float2bfloat16(v);
                    bf16 lb = __float2bfloat16(v - b2f(hb));
                    unsigned short hu, lu;
                    __builtin_memcpy(&hu, &hb, 2); __builtin_memcpy(&lu, &lb, 2);
                    int loff = row * ASTR + ((c * 2) ^ ((row & 7) << 4));
                    *(unsigned short*)(AhiN + loff) = hu;
                    *(unsigned short*)(AloN + loff) = lu;
                    st4_sc(slot + (size_t)row * HSZ + c, (unsigned)hu | ((unsigned)lu << 16));
                }
            }
            asm volatile("s_waitcnt vmcnt(0)" ::: "memory");
            __syncthreads();
            if (tid == 0) { st4i(myprod, t + 1); st4i(mycons, t + 1); }
        }

    } else if (bid < 48) {
        // ===== stage L1a: z[t] = h0[t]@Wih1 + bih1 + bhh1 (feed-forward) =====
        const int r = bid - 32;
        const bf16* Whi = ws + O_WIH1HI; const bf16* Wlo = ws + O_WIH1LO;
        char* Ahi = smem; char* Alo = smem + APLANE;
        int* myprod = PROD + (32 + r) * 16;
        int* mycons = CONS + (32 + r) * 16;
        const int* pprod = PROD + (16 + r) * 16;          // L0
        const int* ccons = CONS + (48 + r) * 16;          // L1b consumed
        const unsigned* h0ring = (const unsigned*)((char*)ws + O_H0RING) + (size_t)r * GRPW;
        float* zring = (float*)((char*)ws + O_ZRING) + (size_t)r * GRPW;
        const int colbase = wv * 64;
        float bias[4];
#pragma unroll
        for (int ni = 0; ni < 4; ni++) { int c = colbase + ni*16 + l15; bias[ni] = bih1[c] + bhh1[c]; }

        for (int t = 0; t < TLEN; ++t) {
            if (t >= 2) pollw(ccons, t - 1, wv);          // z-slot t-2 consumed by L1b
            pollw(pprod, t + 1, wv);                      // h0[t] ready
            u32x4 pf[4];
            pref4sc(h0ring + (size_t)(t & 1) * SLOTW, tid, pf);
            awrite4(Ahi, Alo, tid, pf, 0);
            __syncthreads();
            if (tid == 0) st4i(mycons, t + 1);            // early release of h0 slot
            f32x4 accA[4] = {}, accB[4] = {};
            kloop512(Ahi, Alo, Whi, Wlo, l15, quad, colbase, accA, accB);
            f32x4 zv[4];
#pragma unroll
            for (int ni = 0; ni < 4; ni++)
#pragma unroll
                for (int rr = 0; rr < 4; rr++) zv[ni][rr] = accA[ni][rr] + accB[ni][rr] + bias[ni];
            st16sc(zring + (size_t)(t & 1) * SLOTW + tid * 16, zv);
            asm volatile("s_waitcnt vmcnt(0)" ::: "memory");
            __syncthreads();
            if (tid == 0) st4i(myprod, t + 1);
        }

    } else if (bid < 64) {
        // ===== stage L1b: h1[t] = tanh(z[t] + h1[t-1]@Whh1); state in LDS dbuf =====
        const int r = bid - 48;
        const bf16* Whi = ws + O_WHH1HI; const bf16* Wlo = ws + O_WHH1LO;
        char* A0 = smem;
        int* myprod = PROD + (48 + r) * 16;
        int* mycons = CONS + (48 + r) * 16;
        const int* pprod = PROD + (32 + r) * 16;          // L1a
        const int* ccons = CONS + (64 + (r >> 1)) * 16;   // FC consumed
        const float* zring = (const float*)((char*)ws + O_ZRING) + (size_t)r * GRPW;
        unsigned* h1ring = (unsigned*)((char*)ws + O_H1RING) + (size_t)r * GRPW;
        const int colbase = wv * 64;

        for (int i = tid * 4; i < 2 * APLANE; i += 512 * 4) *(unsigned*)(A0 + i) = 0u;  // h1[-1]=0
        __syncthreads();

        for (int t = 0; t < TLEN; ++t) {
            const int cur = t & 1;
            const char* Ahi = A0 + (cur*2 + 0) * APLANE;
            const char* Alo = A0 + (cur*2 + 1) * APLANE;
            char* AhiN = A0 + ((cur^1)*2 + 0) * APLANE;
            char* AloN = A0 + ((cur^1)*2 + 1) * APLANE;
            if (t >= 2) pollw(ccons, t - 1, wv);          // FC done with h1 slot t-2
            f32x4 accA[4] = {}, accB[4] = {};
            kloop512(Ahi, Alo, Whi, Wlo, l15, quad, colbase, accA, accB);
            pollw(pprod, t + 1, wv);                      // z[t] ready
            f32x4 zc[4];
            ld64sc(zring + (size_t)(t & 1) * SLOTW + tid * 16, zc);
            unsigned* slot = h1ring + (size_t)(t & 1) * SLOTW;
#pragma unroll
            for (int ni = 0; ni < 4; ni++) {
                int c = colbase + ni*16 + l15;
#pragma unroll
                for (int rr = 0; rr < 4; rr++) {
                    int row = quad*4 + rr;
                    float v = tanhf(accA[ni][rr] + accB[ni][rr] + zc[ni][rr]);
                    bf16 hb = __float2bfloat16(v);
                    bf16 lb = __float2bfloat16(v - b2f(hb));
                    unsigned short hu, lu;
                    __builtin_memcpy(&hu, &hb, 2); __builtin_memcpy(&lu, &lb, 2);
                    int loff = row * ASTR + ((c * 2) ^ ((row & 7) << 4));
                    *(unsigned short*)(AhiN + loff) = hu;
                    *(unsigned short*)(AloN + loff) = lu;
                    st4_sc(slot + (size_t)row * HSZ + c, (unsigned)hu | ((unsigned)lu << 16));
                }
            }
            asm volatile("s_waitcnt vmcnt(0)" ::: "memory");
            __syncthreads();
            if (tid == 0) { st4i(myprod, t + 1); st4i(mycons, t + 1); }
        }

    } else {
        // ===== stage FC: logits[:,t,:] = h1[t] @ Wfc + bfc (32 rows/block) =====
        const int f = bid - 64, mb = f * 32;
        const bf16* Whi = ws + O_WFCHI; const bf16* Wlo = ws + O_WFCLO;
        char* Ahi = smem;                  // 32 rows x 1024B (swizzled)
        char* Alo = smem + 32768;
        int* mycons = CONS + (64 + f) * 16;
        const int* p1 = PROD + (48 + 2*f) * 16;
        const int* p2 = PROD + (48 + 2*f + 1) * 16;
        const unsigned* ring1 = (const unsigned*)((char*)ws + O_H1RING) + (size_t)(2*f) * GRPW;
        const unsigned* ring2 = (const unsigned*)((char*)ws + O_H1RING) + (size_t)(2*f + 1) * GRPW;
        const int col = wv * 16 + l15;
        const float bias = bfc[col];
        const bf16* wh = Whi + (size_t)col * HSZ;
        const bf16* wl = Wlo + (size_t)col * HSZ;
        const int swz = (l15 & 7) << 4;

        for (int t = 0; t < TLEN; ++t) {
            pollw(p1, t + 1, wv);
            pollw(p2, t + 1, wv);                          // also fences prior k-loop LDS reads
            u32x4 pf[8];
            pref8sc(ring1 + (size_t)(t & 1) * SLOTW, ring2 + (size_t)(t & 1) * SLOTW, tid, pf);
            awrite4(Ahi, Alo, tid, pf, 0);
            awrite4(Ahi, Alo, tid, pf + 4, 16);
            __syncthreads();
            if (tid == 0) st4i(mycons, t + 1);             // release h1 slots early
            f32x4 accA[2] = {}, accB[2] = {};
#pragma unroll 4
            for (int kc = 0; kc < 16; kc++) {
                short8 bh = ld8(wh + kc*32 + quad*8);
                short8 bl = ld8(wl + kc*32 + quad*8);
#pragma unroll
                for (int mi = 0; mi < 2; mi++) {
                    int aoff = (mi*16 + l15) * ASTR + ((kc*64 + quad*16) ^ swz);
                    short8 ah = *(const short8*)(Ahi + aoff);
                    short8 al = *(const short8*)(Alo + aoff);
                    accA[mi] = MFMA(ah, bh, accA[mi]);
                    accB[mi] = MFMA(al, bh, accB[mi]);
                    accB[mi] = MFMA(ah, bl, accB[mi]);
                }
            }
#pragma unroll
            for (int mi = 0; mi < 2; mi++)
#pragma unroll
                for (int rr = 0; rr < 4; rr++) {
                    int row = mb + mi*16 + quad*4 + rr;
                    out[((size_t)row * TLEN + t) * VSZ + col] = accA[mi][rr] + accB[mi][rr] + bias;
                }
        }
    }
}

extern "C" void kernel_launch(void* const* d_in, const int* in_sizes, int n_in,
                              void* d_out, int out_size, void* d_ws, size_t ws_size,
                              hipStream_t stream) {
    const int*   x    = (const int*)d_in[0];
    const float* emb  = (const float*)d_in[1];
    const float* Wih0 = (const float*)d_in[2];
    const float* bih0 = (const float*)d_in[3];
    const float* Whh0 = (const float*)d_in[4];
    const float* bhh0 = (const float*)d_in[5];
    const float* Wih1 = (const float*)d_in[6];
    const float* bih1 = (const float*)d_in[7];
    const float* Whh1 = (const float*)d_in[8];
    const float* bhh1 = (const float*)d_in[9];
    const float* Wfc  = (const float*)d_in[10];
    const float* bfc  = (const float*)d_in[11];
    float* out = (float*)d_out;
    bf16* ws   = (bf16*)d_ws;

    const int total = 3 * HSZ * HSZ + HSZ * EMBD + VSZ * HSZ + VSZ * EMBD + NBLK * 16 * 2;
    k_prep<<<(total + 255) / 256, 256, 0, stream>>>(emb, Wih0, Whh0, Wih1, Whh1, Wfc, ws);

    k_persist<<<NBLK, 512, SMEMSZ, stream>>>(x, bih0, bhh0, bih1, bhh1, bfc, ws, out);
}